// Round 1
// baseline (732.151 us; speedup 1.0000x reference)
//
#include <hip/hip_runtime.h>

#define NN 65536
#define BB 64
#define HH 1024
#define MM 64
#define RR 4

__device__ __forceinline__ float waveReduceSum(float v) {
#pragma unroll
  for (int off = 32; off > 0; off >>= 1) v += __shfl_xor(v, off, 64);
  return v;
}

__device__ __forceinline__ float fastPow(float wt, float p) {
  return __expf(p * __logf(wt));
}

// shifted, gated interpolation weight at n (lane == n % 64). (used by wpow0)
__device__ __forceinline__ float shifted_wg(
    const float* __restrict__ Eb, const float* __restrict__ wb, int n,
    float gb, float rinv, float s0, float s1, float s2) {
  const int lane = threadIdx.x & 63;
  const float omg = 1.f - gb;
  const float wgc = gb * Eb[n] * rinv + omg * wb[n];
  float wgm = __shfl_up(wgc, 1, 64);
  float wgp = __shfl_down(wgc, 1, 64);
  if (lane == 0)  wgm = (n > 0)      ? (gb * Eb[n - 1] * rinv + omg * wb[n - 1]) : 0.f;
  if (lane == 63) wgp = (n < NN - 1) ? (gb * Eb[n + 1] * rinv + omg * wb[n + 1]) : 0.f;
  return s0 * wgm + s1 * wgc + s2 * wgp;
}

// ---------------------------------------------------------------------------
// K1: fused prep (prep1+prep2). grid 64 (one block per b), block 256.
// Also zero-inits RS0p/RS1p/GSp (contiguous 37888 floats at zbase).
// ---------------------------------------------------------------------------
__global__ __launch_bounds__(256) void prep_kernel(
    const float* __restrict__ h_t,
    const float* __restrict__ key_w, const float* __restrict__ key_b,
    const float* __restrict__ erase_w, const float* __restrict__ erase_b,
    const float* __restrict__ add_w, const float* __restrict__ add_b,
    const float* __restrict__ beta_w, const float* __restrict__ beta_b,
    const float* __restrict__ gate_w, const float* __restrict__ gate_b,
    const float* __restrict__ shift_w, const float* __restrict__ shift_b,
    const float* __restrict__ gamma_w, const float* __restrict__ gamma_b,
    float* __restrict__ kn, float* __restrict__ e_v, float* __restrict__ a_v,
    float* __restrict__ g, float* __restrict__ gamma_, float* __restrict__ s,
    float* __restrict__ betaGlob, float* __restrict__ zbase)
{
  const int b = blockIdx.x;
  const int t = threadIdx.x;
  for (int i = b * 256 + t; i < 37888; i += 16384) zbase[i] = 0.f;
  __shared__ float h_sh[HH];
  __shared__ float red[3][64][4];
  __shared__ float k_sh[64];
  ((float4*)h_sh)[t] = ((const float4*)(h_t + (size_t)b * HH))[t];
  __syncthreads();
  const int c = t & 63, q = t >> 6;
#pragma unroll
  for (int mat = 0; mat < 3; mat++) {
    const float* __restrict__ Wm = (mat == 0) ? key_w : ((mat == 1) ? erase_w : add_w);
    float d = 0.f;
#pragma unroll 8
    for (int i = 0; i < 256; i++)
      d += h_sh[q * 256 + i] * Wm[(q * 256 + i) * 64 + c];
    red[mat][c][q] = d;
  }
  __syncthreads();
  if (t < 64) {
    const float v = red[0][t][0] + red[0][t][1] + red[0][t][2] + red[0][t][3];
    k_sh[t] = fminf(fmaxf(v + key_b[t], 0.f), 1.f);
  } else if (t < 128) {
    const int c2 = t - 64;
    const float v = red[1][c2][0] + red[1][c2][1] + red[1][c2][2] + red[1][c2][3];
    e_v[b * 64 + c2] = fminf(fmaxf(v + erase_b[c2], 0.f), 1.f);
  } else if (t < 192) {
    const int c2 = t - 128;
    const float v = red[2][c2][0] + red[2][c2][1] + red[2][c2][2] + red[2][c2][3];
    a_v[b * 64 + c2] = fminf(fmaxf(v + add_b[c2], 0.f), 1.f);
  } else {
    const int lane = t - 192;
    float o0 = 0.f, o1 = 0.f, o2 = 0.f, o3 = 0.f, o4 = 0.f, o5 = 0.f;
#pragma unroll 4
    for (int k = 0; k < 16; k++) {
      const int hh = lane + k * 64;
      const float hv = h_sh[hh];
      o0 += hv * beta_w[hh];
      o1 += hv * gate_w[hh];
      o2 += hv * gamma_w[hh];
      o3 += hv * shift_w[hh * 3 + 0];
      o4 += hv * shift_w[hh * 3 + 1];
      o5 += hv * shift_w[hh * 3 + 2];
    }
    o0 = waveReduceSum(o0); o1 = waveReduceSum(o1); o2 = waveReduceSum(o2);
    o3 = waveReduceSum(o3); o4 = waveReduceSum(o4); o5 = waveReduceSum(o5);
    if (lane == 0) {
      betaGlob[b] = fmaxf(o0 + beta_b[0], 0.f);
      g[b]        = fminf(fmaxf(o1 + gate_b[0], 0.f), 1.f);
      gamma_[b]   = 1.0f + fmaxf(o2 + gamma_b[0], 0.f);
      const float l0 = o3 + shift_b[0], l1 = o4 + shift_b[1], l2 = o5 + shift_b[2];
      const float mx = fmaxf(l0, fmaxf(l1, l2));
      const float e0 = __expf(l0 - mx), e1 = __expf(l1 - mx), e2 = __expf(l2 - mx);
      const float inv = 1.f / (e0 + e1 + e2);
      s[b * 3 + 0] = e0 * inv; s[b * 3 + 1] = e1 * inv; s[b * 3 + 2] = e2 * inv;
    }
  }
  __syncthreads();
  if (t < 64) {
    float ss = 0.f;
    for (int j = 0; j < 64; j++) ss += k_sh[j] * k_sh[j];
    kn[b * 64 + t] = k_sh[t] / (sqrtf(ss) + 1e-8f);
  }
}

// ---------------------------------------------------------------------------
// K2: content addressing on bank m0, each memory row read ONCE.
// grid 256, block 256, one thread per n. Loops all 64 b (kn uniform -> s-loads).
// ---------------------------------------------------------------------------
__global__ __launch_bounds__(256) void content0_kernel(
    const float* __restrict__ mem, const int* __restrict__ bank,
    const float* __restrict__ kn, const float* __restrict__ beta,
    float* __restrict__ E, float* __restrict__ RSp)
{
  const float* Mrow = mem + (size_t)(*bank) * (size_t)NN * MM;
  const int t = threadIdx.x;
  const int n = blockIdx.x * 256 + t;
  const int lane = t & 63;
  __shared__ float rs_sh[64];
  if (t < 64) rs_sh[t] = 0.f;
  float4 row[16];
  const float4* rp = (const float4*)(Mrow + (size_t)n * MM);
#pragma unroll
  for (int q = 0; q < 16; q++) row[q] = rp[q];
  float ss = 0.f;
#pragma unroll
  for (int q = 0; q < 16; q++)
    ss += row[q].x * row[q].x + row[q].y * row[q].y + row[q].z * row[q].z + row[q].w * row[q].w;
  const float rinv = 1.0f / (sqrtf(ss) + 1e-8f);
  __syncthreads();
  for (int b = 0; b < 64; b++) {
    const float4* kp = (const float4*)(kn + b * 64);  // uniform address -> scalar loads
    float dot = 0.f;
#pragma unroll
    for (int q = 0; q < 16; q++) {
      const float4 kq = kp[q];
      dot += kq.x * row[q].x + kq.y * row[q].y + kq.z * row[q].z + kq.w * row[q].w;
    }
    const float e = __expf(beta[b] * dot * rinv);
    E[(size_t)b * NN + n] = e;
    const float r = waveReduceSum(e);
    if (lane == 0) atomicAdd(&rs_sh[b], r);
  }
  __syncthreads();
  if (t < 64) atomicAdd(&RSp[t * 256 + (blockIdx.x & 15) * 16], rs_sh[t]);
}

// ---------------------------------------------------------------------------
// K3: streaming w_pow producer for the WRITE head. grid (64, 64), block 256.
// (unchanged from verified kernel)
// ---------------------------------------------------------------------------
__global__ __launch_bounds__(256) void wpow_kernel(
    const float* __restrict__ E, const float* __restrict__ wprev,
    const float* __restrict__ RSp, const float* __restrict__ g,
    const float* __restrict__ gamma_, const float* __restrict__ s,
    float* __restrict__ W, float* __restrict__ GSp, int slot)
{
  const int b = blockIdx.y;
  const float gb = g[b], gmb = gamma_[b];
  const float s0 = s[b * 3], s1 = s[b * 3 + 1], s2 = s[b * 3 + 2];
  float rs = 0.f;
#pragma unroll
  for (int j = 0; j < 16; j++) rs += RSp[b * 256 + j * 16];
  const float rinv = 1.0f / rs;
  const float* Eb = E + (size_t)b * NN;
  const float* wb = wprev + (size_t)b * NN;
  float* Wb = W + (size_t)b * NN;
  const int base = blockIdx.x * 1024;
  float acc = 0.f;
#pragma unroll
  for (int k = 0; k < 4; k++) {
    const int n = base + k * 256 + threadIdx.x;
    const float wt = shifted_wg(Eb, wb, n, gb, rinv, s0, s1, s2);
    const float wp = fastPow(wt, gmb);
    Wb[n] = wp;
    acc += wp;
  }
  __shared__ float wsum[4];
  const float w = waveReduceSum(acc);
  if ((threadIdx.x & 63) == 0) wsum[threadIdx.x >> 6] = w;
  __syncthreads();
  if (threadIdx.x == 0)
    atomicAdd(&GSp[slot * 1024 + b * 16], wsum[0] + wsum[1] + wsum[2] + wsum[3]);
}

// ---------------------------------------------------------------------------
// K4: apply write head + FUSED content addressing of m1 (E1 + RS1 partials).
// grid 1024 (64-n tiles), block 256. m1 rows leave in registers -> E1 free.
// ---------------------------------------------------------------------------
__global__ __launch_bounds__(256) void apply_content_kernel(
    const float* __restrict__ W0, const float* __restrict__ GSp,
    const float* __restrict__ e_v, const float* __restrict__ a_v,
    const float* __restrict__ memory, const int* __restrict__ bank,
    const float* __restrict__ kn, const float* __restrict__ beta,
    float* __restrict__ m1, float* __restrict__ E1, float* __restrict__ RSp)
{
  __shared__ float cw[64 * 68];
  __shared__ float e_sh[4096];
  __shared__ float a_sh[4096];
  __shared__ float kn_sh[4096];
  __shared__ float beta_sh[64];
  __shared__ float rs_sh[64];
  const int t = threadIdx.x;
  const int n0 = blockIdx.x * 64;
  float gs = 0.f;
#pragma unroll
  for (int j = 0; j < 64; j++) gs += GSp[j * 16];
  const float invGS = 1.0f / (gs + 1e-5f);
#pragma unroll
  for (int qq = 0; qq < 4; qq++) {
    ((float4*)e_sh)[t + 256 * qq] = ((const float4*)e_v)[t + 256 * qq];
    ((float4*)a_sh)[t + 256 * qq] = ((const float4*)a_v)[t + 256 * qq];
    ((float4*)kn_sh)[t + 256 * qq] = ((const float4*)kn)[t + 256 * qq];
  }
  if (t < 64) { beta_sh[t] = beta[t]; rs_sh[t] = 0.f; }
#pragma unroll
  for (int rep = 0; rep < 4; rep++) {
    const int idx = rep * 256 + t;
    const int b = idx >> 4, nc = idx & 15;
    float4 v = *((const float4*)(W0 + (size_t)b * NN + n0 + nc * 4));
    v.x *= invGS; v.y *= invGS; v.z *= invGS; v.w *= invGS;
    *((float4*)&cw[b * 68 + nc * 4]) = v;
  }
  __syncthreads();
  const int nl = t >> 2, mq = t & 3;
  const int n = n0 + nl;
  float er[16], ad[16];
#pragma unroll
  for (int j = 0; j < 16; j++) { er[j] = 0.f; ad[j] = 0.f; }
  for (int b = 0; b < 64; b++) {
    const float c = cw[b * 68 + nl];
#pragma unroll
    for (int j = 0; j < 4; j++) {
      const float4 ev = *((const float4*)&e_sh[b * 64 + mq * 16 + j * 4]);
      const float4 av = *((const float4*)&a_sh[b * 64 + mq * 16 + j * 4]);
      er[j * 4 + 0] += c * ev.x; er[j * 4 + 1] += c * ev.y;
      er[j * 4 + 2] += c * ev.z; er[j * 4 + 3] += c * ev.w;
      ad[j * 4 + 0] += c * av.x; ad[j * 4 + 1] += c * av.y;
      ad[j * 4 + 2] += c * av.z; ad[j * 4 + 3] += c * av.w;
    }
  }
  const float* M0 = memory + (size_t)(*bank) * (size_t)NN * MM;
  const float4* m0p = (const float4*)(M0 + (size_t)n * MM + mq * 16);
  float4* m1p = (float4*)(m1 + (size_t)n * MM + mq * 16);
  float4 o4[4];
#pragma unroll
  for (int j = 0; j < 4; j++) {
    const float4 mv = m0p[j];
    o4[j].x = mv.x * (1.f - er[j * 4 + 0]) + ad[j * 4 + 0];
    o4[j].y = mv.y * (1.f - er[j * 4 + 1]) + ad[j * 4 + 1];
    o4[j].z = mv.z * (1.f - er[j * 4 + 2]) + ad[j * 4 + 2];
    o4[j].w = mv.w * (1.f - er[j * 4 + 3]) + ad[j * 4 + 3];
    m1p[j] = o4[j];
  }
  // fused content addressing of the just-computed m1 row
  float ssq = 0.f;
#pragma unroll
  for (int j = 0; j < 4; j++)
    ssq += o4[j].x * o4[j].x + o4[j].y * o4[j].y + o4[j].z * o4[j].z + o4[j].w * o4[j].w;
  ssq += __shfl_xor(ssq, 1, 64);
  ssq += __shfl_xor(ssq, 2, 64);
  const float rinv = 1.0f / (sqrtf(ssq) + 1e-8f);
  for (int b = 0; b < 64; b++) {
    float dot = 0.f;
#pragma unroll
    for (int j = 0; j < 4; j++) {
      const float4 kv = *((const float4*)&kn_sh[b * 64 + mq * 16 + j * 4]);
      dot += kv.x * o4[j].x + kv.y * o4[j].y + kv.z * o4[j].z + kv.w * o4[j].w;
    }
    dot += __shfl_xor(dot, 1, 64);
    dot += __shfl_xor(dot, 2, 64);
    const float e = __expf(beta_sh[b] * dot * rinv);
    if (mq == 0) E1[(size_t)b * NN + n] = e;
    float contrib = (mq == 0) ? e : 0.f;
    contrib += __shfl_xor(contrib, 4, 64);
    contrib += __shfl_xor(contrib, 8, 64);
    contrib += __shfl_xor(contrib, 16, 64);
    contrib += __shfl_xor(contrib, 32, 64);
    if ((t & 63) == 0) atomicAdd(&rs_sh[b], contrib);
  }
  __syncthreads();
  if (t < 64) atomicAdd(&RSp[t * 256 + (blockIdx.x & 15) * 16], rs_sh[t]);
}

// ---------------------------------------------------------------------------
// K5: ALL FOUR read heads fused: per 64-n tile, compute w_pow tile into LDS
// (no W materialization) and contract against LDS-resident m1 tile.
// grid 512 (2 sub-tiles each), block 256. part[512][4][64][64] + GS partials.
// ---------------------------------------------------------------------------
__global__ __launch_bounds__(256) void heads_kernel(
    const float* __restrict__ E, const float* __restrict__ wr,
    const float* __restrict__ m1, const float* __restrict__ RSp,
    const float* __restrict__ g, const float* __restrict__ gamma_,
    const float* __restrict__ s,
    float* __restrict__ part, float* __restrict__ GSp)
{
  __shared__ float g_sh[64], gm_sh[64], ri_sh[64];
  __shared__ float s0_sh[64], s1_sh[64], s2_sh[64];
  __shared__ float m1_sh[64 * 68];
  __shared__ float w_sh[64 * 68];
  __shared__ float gsred[4][4];
  const int t = threadIdx.x;
  if (t < 64) {
    float rs = 0.f;
#pragma unroll
    for (int j = 0; j < 16; j++) rs += RSp[t * 256 + j * 16];
    ri_sh[t] = 1.0f / rs;
    g_sh[t] = g[t];
    gm_sh[t] = gamma_[t];
    s0_sh[t] = s[t * 3 + 0];
    s1_sh[t] = s[t * 3 + 1];
    s2_sh[t] = s[t * 3 + 2];
  }
  __syncthreads();
  const int bq = t >> 4, mq = t & 15;
  const int n_l = t & 63, bg = t >> 6;
  const int lane = n_l;
  float4 acc[RR][4];
#pragma unroll
  for (int r = 0; r < RR; r++)
#pragma unroll
    for (int j = 0; j < 4; j++) acc[r][j] = make_float4(0.f, 0.f, 0.f, 0.f);
  float gs_acc[RR] = {0.f, 0.f, 0.f, 0.f};

  for (int st = 0; st < 2; st++) {
    const int n0 = (blockIdx.x * 2 + st) * 64;
    const int n = n0 + n_l;
    // stage m1 tile (previous gemm synced at end of last r)
#pragma unroll
    for (int rep = 0; rep < 4; rep++) {
      const int nl2 = rep * 16 + (t >> 4);
      const int mc = t & 15;
      *((float4*)&m1_sh[nl2 * 68 + mc * 4]) =
          ((const float4*)(m1 + (size_t)(n0 + nl2) * MM))[mc];
    }
    // cache r-independent content part g*E/RS in registers for this sub-tile
    float e_c[16];
#pragma unroll
    for (int bb = 0; bb < 16; bb++) {
      const int b = bg * 16 + bb;
      e_c[bb] = g_sh[b] * ri_sh[b] * E[(size_t)b * NN + n];
    }
#pragma unroll
    for (int r = 0; r < RR; r++) {
      const float* __restrict__ wrr = wr + (size_t)r * BB * NN;
#pragma unroll
      for (int bb = 0; bb < 16; bb++) {
        const int b = bg * 16 + bb;
        const float omg = 1.f - g_sh[b];
        const float* __restrict__ wb = wrr + (size_t)b * NN;
        const float wgc = e_c[bb] + omg * wb[n];
        float wgm = __shfl_up(wgc, 1, 64);
        float wgp = __shfl_down(wgc, 1, 64);
        if (lane == 0) {
          const float gri = g_sh[b] * ri_sh[b];
          wgm = (n > 0) ? (gri * E[(size_t)b * NN + n - 1] + omg * wb[n - 1]) : 0.f;
        }
        if (lane == 63) {
          const float gri = g_sh[b] * ri_sh[b];
          wgp = (n < NN - 1) ? (gri * E[(size_t)b * NN + n + 1] + omg * wb[n + 1]) : 0.f;
        }
        const float wt = s0_sh[b] * wgm + s1_sh[b] * wgc + s2_sh[b] * wgp;
        const float wp = fastPow(wt, gm_sh[b]);
        w_sh[b * 68 + n_l] = wp;
        gs_acc[r] += wp;
      }
      __syncthreads();  // w_sh (and m1_sh on r==0) visible
#pragma unroll 4
      for (int nn = 0; nn < 64; nn++) {
        const float4 mv = *((const float4*)&m1_sh[nn * 68 + mq * 4]);
        const float w0 = w_sh[(bq * 4 + 0) * 68 + nn];
        const float w1 = w_sh[(bq * 4 + 1) * 68 + nn];
        const float w2 = w_sh[(bq * 4 + 2) * 68 + nn];
        const float w3 = w_sh[(bq * 4 + 3) * 68 + nn];
        acc[r][0].x += w0 * mv.x; acc[r][0].y += w0 * mv.y; acc[r][0].z += w0 * mv.z; acc[r][0].w += w0 * mv.w;
        acc[r][1].x += w1 * mv.x; acc[r][1].y += w1 * mv.y; acc[r][1].z += w1 * mv.z; acc[r][1].w += w1 * mv.w;
        acc[r][2].x += w2 * mv.x; acc[r][2].y += w2 * mv.y; acc[r][2].z += w2 * mv.z; acc[r][2].w += w2 * mv.w;
        acc[r][3].x += w3 * mv.x; acc[r][3].y += w3 * mv.y; acc[r][3].z += w3 * mv.z; acc[r][3].w += w3 * mv.w;
      }
      __syncthreads();  // gemm done before w_sh/m1_sh overwritten
    }
  }
  float* pp = part + (size_t)blockIdx.x * (RR * 4096);
#pragma unroll
  for (int r = 0; r < RR; r++)
#pragma unroll
    for (int j = 0; j < 4; j++)
      *((float4*)&pp[r * 4096 + (bq * 4 + j) * 64 + mq * 4]) = acc[r][j];
#pragma unroll
  for (int r = 0; r < RR; r++) {
    const float v = waveReduceSum(gs_acc[r]);
    if (lane == 0) gsred[t >> 6][r] = v;
  }
  __syncthreads();
  if (t < 4)
    atomicAdd(&GSp[(1 + t) * 1024 + (blockIdx.x & 63) * 16],
              gsred[0][t] + gsred[1][t] + gsred[2][t] + gsred[3][t]);
}

// ---------------------------------------------------------------------------
// K6: reduce 512 part slabs + normalize by GS_r. grid 64 (one per b), block 1024.
// ---------------------------------------------------------------------------
__global__ __launch_bounds__(1024) void finalize_kernel(
    const float* __restrict__ part, const float* __restrict__ GSp,
    float* __restrict__ out)
{
  __shared__ float gs_sh[4];
  __shared__ float4 red[16][64];
  const int t = threadIdx.x;
  if (t < 256) {
    const int wv = t >> 6, ln = t & 63;
    float v = GSp[(1 + wv) * 1024 + ln * 16];
    v = waveReduceSum(v);
    if (ln == 0) gs_sh[wv] = v;
  }
  const int b = blockIdx.x;
  const int q16 = t >> 6, fi = t & 63;
  const int r = fi >> 4, mf = fi & 15;
  const float4* p4 = (const float4*)part;
  const size_t base = (size_t)r * 1024 + b * 16 + mf;
  float4 sum = make_float4(0.f, 0.f, 0.f, 0.f);
#pragma unroll 8
  for (int sc = q16 * 32; sc < q16 * 32 + 32; sc++) {
    const float4 v = p4[(size_t)sc * 4096 + base];
    sum.x += v.x; sum.y += v.y; sum.z += v.z; sum.w += v.w;
  }
  red[q16][fi] = sum;
  __syncthreads();
  if (t < 64) {
    const int rr = t >> 4;
    float4 tot = make_float4(0.f, 0.f, 0.f, 0.f);
#pragma unroll
    for (int k = 0; k < 16; k++) {
      const float4 v = red[k][t];
      tot.x += v.x; tot.y += v.y; tot.z += v.z; tot.w += v.w;
    }
    const float inv = 1.0f / (gs_sh[rr] + 1e-5f);
    tot.x *= inv; tot.y *= inv; tot.z *= inv; tot.w *= inv;
    ((float4*)out)[b * 64 + t] = tot;
  }
}

// ---------------------------------------------------------------------------
extern "C" void kernel_launch(void* const* d_in, const int* in_sizes, int n_in,
                              void* d_out, int out_size, void* d_ws, size_t ws_size,
                              hipStream_t stream) {
  (void)in_sizes; (void)n_in; (void)out_size; (void)ws_size;
  const float* h_t    = (const float*)d_in[0];
  const float* ww     = (const float*)d_in[1];
  const float* wr     = (const float*)d_in[2];
  const float* memory = (const float*)d_in[3];
  const float* key_w  = (const float*)d_in[4];
  const float* key_b  = (const float*)d_in[5];
  const float* beta_w = (const float*)d_in[6];
  const float* beta_b = (const float*)d_in[7];
  const float* gate_w = (const float*)d_in[8];
  const float* gate_b = (const float*)d_in[9];
  const float* shift_w = (const float*)d_in[10];
  const float* shift_b = (const float*)d_in[11];
  const float* gamma_w = (const float*)d_in[12];
  const float* gamma_b = (const float*)d_in[13];
  const float* erase_w = (const float*)d_in[14];
  const float* erase_b = (const float*)d_in[15];
  const float* add_w   = (const float*)d_in[16];
  const float* add_b   = (const float*)d_in[17];
  const int*   bank    = (const int*)d_in[18];

  float* ws = (float*)d_ws;
  // slabs (floats): E0 @0, W0 @4M, m1 @8M, E1 @12M.
  // part (8M floats = 32MB) aliases E0+W0 (both dead before heads_kernel).
  float* E0   = ws;
  float* W0   = ws + 4194304;
  float* m1   = ws + 8388608;
  float* E1   = ws + 12582912;
  float* part = ws;
  float* smallb = ws + 16777216;
  float* kn    = smallb;            // 4096
  float* e_v   = smallb + 4096;     // 4096
  float* a_v   = smallb + 8192;     // 4096
  float* betaB = smallb + 12288;    // 64
  float* g     = smallb + 12352;    // 64
  float* gam   = smallb + 12416;    // 64
  float* s     = smallb + 12480;    // 256 (192 used)
  float* RS0p  = smallb + 12800;    // 16384 (64 b x 16 slots x 16 pad)
  float* RS1p  = smallb + 29184;    // 16384
  float* GSp   = smallb + 45568;    // 5120 (5 slots x 64 x 16 pad)
  // RS0p/RS1p/GSp are contiguous: zero range = smallb+12800 .. +50688

  prep_kernel<<<64, 256, 0, stream>>>(
      h_t, key_w, key_b, erase_w, erase_b, add_w, add_b,
      beta_w, beta_b, gate_w, gate_b, shift_w, shift_b, gamma_w, gamma_b,
      kn, e_v, a_v, g, gam, s, betaB, smallb + 12800);
  content0_kernel<<<256, 256, 0, stream>>>(memory, bank, kn, betaB, E0, RS0p);
  wpow_kernel<<<dim3(64, 64), 256, 0, stream>>>(E0, ww, RS0p, g, gam, s, W0, GSp, 0);
  apply_content_kernel<<<1024, 256, 0, stream>>>(W0, GSp, e_v, a_v, memory, bank,
                                                 kn, betaB, m1, E1, RS1p);
  heads_kernel<<<512, 256, 0, stream>>>(E1, wr, m1, RS1p, g, gam, s, part, GSp);
  finalize_kernel<<<64, 1024, 0, stream>>>(part, GSp, (float*)d_out);
}

// Round 2
// 498.766 us; speedup vs baseline: 1.4679x; 1.4679x over previous
//
#include <hip/hip_runtime.h>

#define NN 65536
#define BB 64
#define HH 1024
#define MM 64
#define RR 4

__device__ __forceinline__ float waveReduceSum(float v) {
#pragma unroll
  for (int off = 32; off > 0; off >>= 1) v += __shfl_xor(v, off, 64);
  return v;
}

__device__ __forceinline__ float fastPow(float wt, float p) {
  return __expf(p * __logf(wt));
}

// shifted, gated interpolation weight at n (lane == n % 64). (used by wpow0)
__device__ __forceinline__ float shifted_wg(
    const float* __restrict__ Eb, const float* __restrict__ wb, int n,
    float gb, float rinv, float s0, float s1, float s2) {
  const int lane = threadIdx.x & 63;
  const float omg = 1.f - gb;
  const float wgc = gb * Eb[n] * rinv + omg * wb[n];
  float wgm = __shfl_up(wgc, 1, 64);
  float wgp = __shfl_down(wgc, 1, 64);
  if (lane == 0)  wgm = (n > 0)      ? (gb * Eb[n - 1] * rinv + omg * wb[n - 1]) : 0.f;
  if (lane == 63) wgp = (n < NN - 1) ? (gb * Eb[n + 1] * rinv + omg * wb[n + 1]) : 0.f;
  return s0 * wgm + s1 * wgc + s2 * wgp;
}

// ---------------------------------------------------------------------------
// K1: fused prep. grid 64 (one block per b), block 256.
// Also zero-inits RS0p/RS1p/GSp (contiguous 37888 floats at zbase).
// ---------------------------------------------------------------------------
__global__ __launch_bounds__(256) void prep_kernel(
    const float* __restrict__ h_t,
    const float* __restrict__ key_w, const float* __restrict__ key_b,
    const float* __restrict__ erase_w, const float* __restrict__ erase_b,
    const float* __restrict__ add_w, const float* __restrict__ add_b,
    const float* __restrict__ beta_w, const float* __restrict__ beta_b,
    const float* __restrict__ gate_w, const float* __restrict__ gate_b,
    const float* __restrict__ shift_w, const float* __restrict__ shift_b,
    const float* __restrict__ gamma_w, const float* __restrict__ gamma_b,
    float* __restrict__ kn, float* __restrict__ e_v, float* __restrict__ a_v,
    float* __restrict__ g, float* __restrict__ gamma_, float* __restrict__ s,
    float* __restrict__ betaGlob, float* __restrict__ zbase)
{
  const int b = blockIdx.x;
  const int t = threadIdx.x;
  for (int i = b * 256 + t; i < 37888; i += 16384) zbase[i] = 0.f;
  __shared__ float h_sh[HH];
  __shared__ float red[3][64][4];
  __shared__ float k_sh[64];
  ((float4*)h_sh)[t] = ((const float4*)(h_t + (size_t)b * HH))[t];
  __syncthreads();
  const int c = t & 63, q = t >> 6;
#pragma unroll
  for (int mat = 0; mat < 3; mat++) {
    const float* __restrict__ Wm = (mat == 0) ? key_w : ((mat == 1) ? erase_w : add_w);
    float d = 0.f;
#pragma unroll 8
    for (int i = 0; i < 256; i++)
      d += h_sh[q * 256 + i] * Wm[(q * 256 + i) * 64 + c];
    red[mat][c][q] = d;
  }
  __syncthreads();
  if (t < 64) {
    const float v = red[0][t][0] + red[0][t][1] + red[0][t][2] + red[0][t][3];
    k_sh[t] = fminf(fmaxf(v + key_b[t], 0.f), 1.f);
  } else if (t < 128) {
    const int c2 = t - 64;
    const float v = red[1][c2][0] + red[1][c2][1] + red[1][c2][2] + red[1][c2][3];
    e_v[b * 64 + c2] = fminf(fmaxf(v + erase_b[c2], 0.f), 1.f);
  } else if (t < 192) {
    const int c2 = t - 128;
    const float v = red[2][c2][0] + red[2][c2][1] + red[2][c2][2] + red[2][c2][3];
    a_v[b * 64 + c2] = fminf(fmaxf(v + add_b[c2], 0.f), 1.f);
  } else {
    const int lane = t - 192;
    float o0 = 0.f, o1 = 0.f, o2 = 0.f, o3 = 0.f, o4 = 0.f, o5 = 0.f;
#pragma unroll 4
    for (int k = 0; k < 16; k++) {
      const int hh = lane + k * 64;
      const float hv = h_sh[hh];
      o0 += hv * beta_w[hh];
      o1 += hv * gate_w[hh];
      o2 += hv * gamma_w[hh];
      o3 += hv * shift_w[hh * 3 + 0];
      o4 += hv * shift_w[hh * 3 + 1];
      o5 += hv * shift_w[hh * 3 + 2];
    }
    o0 = waveReduceSum(o0); o1 = waveReduceSum(o1); o2 = waveReduceSum(o2);
    o3 = waveReduceSum(o3); o4 = waveReduceSum(o4); o5 = waveReduceSum(o5);
    if (lane == 0) {
      betaGlob[b] = fmaxf(o0 + beta_b[0], 0.f);
      g[b]        = fminf(fmaxf(o1 + gate_b[0], 0.f), 1.f);
      gamma_[b]   = 1.0f + fmaxf(o2 + gamma_b[0], 0.f);
      const float l0 = o3 + shift_b[0], l1 = o4 + shift_b[1], l2 = o5 + shift_b[2];
      const float mx = fmaxf(l0, fmaxf(l1, l2));
      const float e0 = __expf(l0 - mx), e1 = __expf(l1 - mx), e2 = __expf(l2 - mx);
      const float inv = 1.f / (e0 + e1 + e2);
      s[b * 3 + 0] = e0 * inv; s[b * 3 + 1] = e1 * inv; s[b * 3 + 2] = e2 * inv;
    }
  }
  __syncthreads();
  if (t < 64) {
    float ss = 0.f;
    for (int j = 0; j < 64; j++) ss += k_sh[j] * k_sh[j];
    kn[b * 64 + t] = k_sh[t] / (sqrtf(ss) + 1e-8f);
  }
}

// ---------------------------------------------------------------------------
// K2 / K5: content addressing (round-0 proven). grid (512, 2), block 256.
// RS partials go to RSp[b*256 + slot*16], slot = blockIdx.x & 15.
// ---------------------------------------------------------------------------
__global__ __launch_bounds__(256) void content_kernel(
    const float* __restrict__ mem, const int* __restrict__ bank,
    const float* __restrict__ kn, const float* __restrict__ beta,
    float* __restrict__ E, float* __restrict__ RSp)
{
  const float* Mrow = mem + (bank ? ((size_t)(*bank) * (size_t)NN * MM) : (size_t)0);
  const int t = threadIdx.x;
  const int nl = t & 127;
  const int n = blockIdx.x * 128 + nl;
  const int bgrp = t >> 7;
  const int nhalf = (t >> 6) & 1;
  const int lane = t & 63;
  const int b0 = blockIdx.y * 32 + bgrp * 16;

  float4 row[16];
  const float4* rp = (const float4*)(Mrow + (size_t)n * MM);
#pragma unroll
  for (int q = 0; q < 16; q++) row[q] = rp[q];
  float ss = 0.f;
#pragma unroll
  for (int q = 0; q < 16; q++)
    ss += row[q].x * row[q].x + row[q].y * row[q].y + row[q].z * row[q].z + row[q].w * row[q].w;
  const float rinv = 1.0f / (sqrtf(ss) + 1e-8f);

  __shared__ float accs[32][2];
  for (int i = 0; i < 16; i++) {
    const int rb = __builtin_amdgcn_readfirstlane(b0 + i);
    const float4* kp = (const float4*)(kn + rb * 64);
    float dot = 0.f;
#pragma unroll
    for (int q = 0; q < 16; q++) {
      const float4 kq = kp[q];
      dot += kq.x * row[q].x + kq.y * row[q].y + kq.z * row[q].z + kq.w * row[q].w;
    }
    const float e = __expf(beta[rb] * dot * rinv);
    E[(size_t)rb * NN + n] = e;
    const float r = waveReduceSum(e);
    if (lane == 0) accs[bgrp * 16 + i][nhalf] = r;
  }
  __syncthreads();
  if (t < 32)
    atomicAdd(&RSp[(blockIdx.y * 32 + t) * 256 + (blockIdx.x & 15) * 16],
              accs[t][0] + accs[t][1]);
}

// ---------------------------------------------------------------------------
// K3: streaming w_pow producer for the WRITE head. grid (64, 64), block 256.
// ---------------------------------------------------------------------------
__global__ __launch_bounds__(256) void wpow_kernel(
    const float* __restrict__ E, const float* __restrict__ wprev,
    const float* __restrict__ RSp, const float* __restrict__ g,
    const float* __restrict__ gamma_, const float* __restrict__ s,
    float* __restrict__ W, float* __restrict__ GSp, int slot)
{
  const int b = blockIdx.y;
  const float gb = g[b], gmb = gamma_[b];
  const float s0 = s[b * 3], s1 = s[b * 3 + 1], s2 = s[b * 3 + 2];
  float rs = 0.f;
#pragma unroll
  for (int j = 0; j < 16; j++) rs += RSp[b * 256 + j * 16];
  const float rinv = 1.0f / rs;
  const float* Eb = E + (size_t)b * NN;
  const float* wb = wprev + (size_t)b * NN;
  float* Wb = W + (size_t)b * NN;
  const int base = blockIdx.x * 1024;
  float acc = 0.f;
#pragma unroll
  for (int k = 0; k < 4; k++) {
    const int n = base + k * 256 + threadIdx.x;
    const float wt = shifted_wg(Eb, wb, n, gb, rinv, s0, s1, s2);
    const float wp = fastPow(wt, gmb);
    Wb[n] = wp;
    acc += wp;
  }
  __shared__ float wsum[4];
  const float w = waveReduceSum(acc);
  if ((threadIdx.x & 63) == 0) wsum[threadIdx.x >> 6] = w;
  __syncthreads();
  if (threadIdx.x == 0)
    atomicAdd(&GSp[slot * 1024 + b * 16], wsum[0] + wsum[1] + wsum[2] + wsum[3]);
}

// ---------------------------------------------------------------------------
// K4: apply write head (round-0 proven). grid 1024 (64-n), block 256.
// ---------------------------------------------------------------------------
__global__ __launch_bounds__(256) void apply_write_kernel(
    const float* __restrict__ W0, const float* __restrict__ GSp,
    const float* __restrict__ e_v, const float* __restrict__ a_v,
    const float* __restrict__ memory, const int* __restrict__ bank,
    float* __restrict__ m1)
{
  __shared__ float cw[64 * 68];
  __shared__ float e_sh[4096];
  __shared__ float a_sh[4096];
  const int t = threadIdx.x;
  const int n0 = blockIdx.x * 64;
  float gs = 0.f;
#pragma unroll
  for (int j = 0; j < 64; j++) gs += GSp[j * 16];
  const float invGS = 1.0f / (gs + 1e-5f);
#pragma unroll
  for (int q = 0; q < 4; q++) {
    ((float4*)e_sh)[t + 256 * q] = ((const float4*)e_v)[t + 256 * q];
    ((float4*)a_sh)[t + 256 * q] = ((const float4*)a_v)[t + 256 * q];
  }
#pragma unroll
  for (int rep = 0; rep < 4; rep++) {
    const int idx = rep * 256 + t;
    const int b = idx >> 4, nc = idx & 15;
    float4 v = *((const float4*)(W0 + (size_t)b * NN + n0 + nc * 4));
    v.x *= invGS; v.y *= invGS; v.z *= invGS; v.w *= invGS;
    *((float4*)&cw[b * 68 + nc * 4]) = v;
  }
  __syncthreads();
  const int nl = t >> 2, mq = t & 3;
  const int n = n0 + nl;
  float er[16], ad[16];
#pragma unroll
  for (int j = 0; j < 16; j++) { er[j] = 0.f; ad[j] = 0.f; }
  for (int b = 0; b < 64; b++) {
    const float c = cw[b * 68 + nl];
#pragma unroll
    for (int j = 0; j < 4; j++) {
      const float4 ev = *((const float4*)&e_sh[b * 64 + mq * 16 + j * 4]);
      const float4 av = *((const float4*)&a_sh[b * 64 + mq * 16 + j * 4]);
      er[j * 4 + 0] += c * ev.x; er[j * 4 + 1] += c * ev.y;
      er[j * 4 + 2] += c * ev.z; er[j * 4 + 3] += c * ev.w;
      ad[j * 4 + 0] += c * av.x; ad[j * 4 + 1] += c * av.y;
      ad[j * 4 + 2] += c * av.z; ad[j * 4 + 3] += c * av.w;
    }
  }
  const float* M0 = memory + (size_t)(*bank) * (size_t)NN * MM;
  const float4* m0p = (const float4*)(M0 + (size_t)n * MM + mq * 16);
  float4* m1p = (float4*)(m1 + (size_t)n * MM + mq * 16);
#pragma unroll
  for (int j = 0; j < 4; j++) {
    const float4 mv = m0p[j];
    float4 o;
    o.x = mv.x * (1.f - er[j * 4 + 0]) + ad[j * 4 + 0];
    o.y = mv.y * (1.f - er[j * 4 + 1]) + ad[j * 4 + 1];
    o.z = mv.z * (1.f - er[j * 4 + 2]) + ad[j * 4 + 2];
    o.w = mv.w * (1.f - er[j * 4 + 3]) + ad[j * 4 + 3];
    m1p[j] = o;
  }
}

// ---------------------------------------------------------------------------
// K6: per-r fused wpow+gemm. grid (256, 4): blockIdx.x = sc2, blockIdx.y = r.
// Each block: 4 sub-tiles of 64 n; w_pow tile -> LDS, contract vs m1 tile.
// W never materialized. part[r][sc2][4096] + GS partials (slot 1+r).
// ---------------------------------------------------------------------------
__global__ __launch_bounds__(256) void rheads_kernel(
    const float* __restrict__ E, const float* __restrict__ wr,
    const float* __restrict__ m1, const float* __restrict__ RSp,
    const float* __restrict__ g, const float* __restrict__ gamma_,
    const float* __restrict__ s,
    float* __restrict__ part, float* __restrict__ GSp)
{
  __shared__ float g_sh[64], gm_sh[64], ri_sh[64];
  __shared__ float s0_sh[64], s1_sh[64], s2_sh[64];
  __shared__ float m1_sh[64 * 68];
  __shared__ float w_sh[64 * 68];
  __shared__ float gsred[4];
  const int sc2 = blockIdx.x, r = blockIdx.y;
  const int t = threadIdx.x;
  if (t < 64) {
    float rs = 0.f;
#pragma unroll
    for (int j = 0; j < 16; j++) rs += RSp[t * 256 + j * 16];
    ri_sh[t] = 1.0f / rs;
    g_sh[t] = g[t];
    gm_sh[t] = gamma_[t];
    s0_sh[t] = s[t * 3 + 0];
    s1_sh[t] = s[t * 3 + 1];
    s2_sh[t] = s[t * 3 + 2];
  }
  __syncthreads();
  const int bq = t >> 4, mq = t & 15;
  const int n_l = t & 63, bg = t >> 6;
  const float* __restrict__ wrr = wr + (size_t)r * BB * NN;
  float4 acc[4];
#pragma unroll
  for (int j = 0; j < 4; j++) acc[j] = make_float4(0.f, 0.f, 0.f, 0.f);
  float gs_acc = 0.f;

  for (int st = 0; st < 4; st++) {
    if (st) __syncthreads();  // prior gemm finished reading LDS
    const int n0 = (sc2 * 4 + st) * 64;
    const int n = n0 + n_l;
    // stage m1 tile
#pragma unroll
    for (int rep = 0; rep < 4; rep++) {
      const int nl2 = rep * 16 + (t >> 4);
      const int mc = t & 15;
      *((float4*)&m1_sh[nl2 * 68 + mc * 4]) =
          ((const float4*)(m1 + (size_t)(n0 + nl2) * MM))[mc];
    }
    // w_pow tile: each wave handles 16 b's for its 64 n-lanes
#pragma unroll
    for (int bb = 0; bb < 16; bb++) {
      const int b = bg * 16 + bb;
      const float gri = g_sh[b] * ri_sh[b];
      const float omg = 1.f - g_sh[b];
      const float* __restrict__ wb = wrr + (size_t)b * NN;
      const float* __restrict__ Eb = E + (size_t)b * NN;
      const float wgc = gri * Eb[n] + omg * wb[n];
      float wgm = __shfl_up(wgc, 1, 64);
      float wgp = __shfl_down(wgc, 1, 64);
      if (n_l == 0)  wgm = (n > 0)      ? (gri * Eb[n - 1] + omg * wb[n - 1]) : 0.f;
      if (n_l == 63) wgp = (n < NN - 1) ? (gri * Eb[n + 1] + omg * wb[n + 1]) : 0.f;
      const float wt = s0_sh[b] * wgm + s1_sh[b] * wgc + s2_sh[b] * wgp;
      const float wp = fastPow(wt, gm_sh[b]);
      w_sh[b * 68 + n_l] = wp;
      gs_acc += wp;
    }
    __syncthreads();
    // gemm accumulate: thread (bq, mq) -> 4 b-rows x 4 m-cols
#pragma unroll 4
    for (int nn = 0; nn < 64; nn++) {
      const float4 mv = *((const float4*)&m1_sh[nn * 68 + mq * 4]);
      const float w0 = w_sh[(bq * 4 + 0) * 68 + nn];
      const float w1 = w_sh[(bq * 4 + 1) * 68 + nn];
      const float w2 = w_sh[(bq * 4 + 2) * 68 + nn];
      const float w3 = w_sh[(bq * 4 + 3) * 68 + nn];
      acc[0].x += w0 * mv.x; acc[0].y += w0 * mv.y; acc[0].z += w0 * mv.z; acc[0].w += w0 * mv.w;
      acc[1].x += w1 * mv.x; acc[1].y += w1 * mv.y; acc[1].z += w1 * mv.z; acc[1].w += w1 * mv.w;
      acc[2].x += w2 * mv.x; acc[2].y += w2 * mv.y; acc[2].z += w2 * mv.z; acc[2].w += w2 * mv.w;
      acc[3].x += w3 * mv.x; acc[3].y += w3 * mv.y; acc[3].z += w3 * mv.z; acc[3].w += w3 * mv.w;
    }
  }
  float* pp = part + ((size_t)r * 256 + sc2) * 4096;
#pragma unroll
  for (int j = 0; j < 4; j++)
    *((float4*)&pp[(bq * 4 + j) * 64 + mq * 4]) = acc[j];
  const float v = waveReduceSum(gs_acc);
  if (n_l == 0) gsred[bg] = v;
  __syncthreads();
  if (t == 0)
    atomicAdd(&GSp[(1 + r) * 1024 + (sc2 & 63) * 16],
              gsred[0] + gsred[1] + gsred[2] + gsred[3]);
}

// ---------------------------------------------------------------------------
// K7: reduce part[4][256][4096] + GS normalize. grid 64 (b), block 1024.
// ---------------------------------------------------------------------------
__global__ __launch_bounds__(1024) void finalize_kernel(
    const float* __restrict__ part, const float* __restrict__ GSp,
    float* __restrict__ out)
{
  __shared__ float gs_sh[4];
  __shared__ float red[4][256];
  const int t = threadIdx.x;
  if (t < 256) {
    const int wv = t >> 6, ln = t & 63;
    float v = GSp[(1 + wv) * 1024 + ln * 16];
    v = waveReduceSum(v);
    if (ln == 0) gs_sh[wv] = v;
  }
  const int b = blockIdx.x;
  const int q = t >> 8;        // slab quarter 0..3
  const int e = t & 255;       // r*64 + m
  const int r = e >> 6, m = e & 63;
  float sum = 0.f;
  const float* pp = part + (size_t)r * 256 * 4096 + (size_t)b * 64 + m;
#pragma unroll 8
  for (int k = q * 64; k < q * 64 + 64; k++)
    sum += pp[(size_t)k * 4096];
  red[q][e] = sum;
  __syncthreads();
  if (t < 256) {
    const float tot = red[0][t] + red[1][t] + red[2][t] + red[3][t];
    out[b * 256 + t] = tot / (gs_sh[t >> 6] + 1e-5f);
  }
}

// ---------------------------------------------------------------------------
extern "C" void kernel_launch(void* const* d_in, const int* in_sizes, int n_in,
                              void* d_out, int out_size, void* d_ws, size_t ws_size,
                              hipStream_t stream) {
  (void)in_sizes; (void)n_in; (void)out_size; (void)ws_size;
  const float* h_t    = (const float*)d_in[0];
  const float* ww     = (const float*)d_in[1];
  const float* wr     = (const float*)d_in[2];
  const float* memory = (const float*)d_in[3];
  const float* key_w  = (const float*)d_in[4];
  const float* key_b  = (const float*)d_in[5];
  const float* beta_w = (const float*)d_in[6];
  const float* beta_b = (const float*)d_in[7];
  const float* gate_w = (const float*)d_in[8];
  const float* gate_b = (const float*)d_in[9];
  const float* shift_w = (const float*)d_in[10];
  const float* shift_b = (const float*)d_in[11];
  const float* gamma_w = (const float*)d_in[12];
  const float* gamma_b = (const float*)d_in[13];
  const float* erase_w = (const float*)d_in[14];
  const float* erase_b = (const float*)d_in[15];
  const float* add_w   = (const float*)d_in[16];
  const float* add_b   = (const float*)d_in[17];
  const int*   bank    = (const int*)d_in[18];

  float* ws = (float*)d_ws;
  // slabs (floats): E0 @0, W0 @4M, m1 @8M, E1 @12M.
  // part (4M floats = 16MB) aliases E0 (dead after wpow0).
  float* E0   = ws;
  float* W0   = ws + 4194304;
  float* m1   = ws + 8388608;
  float* E1   = ws + 12582912;
  float* part = ws;
  float* smallb = ws + 16777216;
  float* kn    = smallb;            // 4096
  float* e_v   = smallb + 4096;     // 4096
  float* a_v   = smallb + 8192;     // 4096
  float* betaB = smallb + 12288;    // 64
  float* g     = smallb + 12352;    // 64
  float* gam   = smallb + 12416;    // 64
  float* s     = smallb + 12480;    // 256 (192 used)
  float* RS0p  = smallb + 12800;    // 16384 (64 b x 16 slots x 16 pad)
  float* RS1p  = smallb + 29184;    // 16384
  float* GSp   = smallb + 45568;    // 5120 (5 slots x 64 x 16 pad)
  // RS0p/RS1p/GSp contiguous: zero range = smallb+12800 .. +50688

  prep_kernel<<<64, 256, 0, stream>>>(
      h_t, key_w, key_b, erase_w, erase_b, add_w, add_b,
      beta_w, beta_b, gate_w, gate_b, shift_w, shift_b, gamma_w, gamma_b,
      kn, e_v, a_v, g, gam, s, betaB, smallb + 12800);
  content_kernel<<<dim3(512, 2), 256, 0, stream>>>(memory, bank, kn, betaB, E0, RS0p);
  wpow_kernel<<<dim3(64, 64), 256, 0, stream>>>(E0, ww, RS0p, g, gam, s, W0, GSp, 0);
  apply_write_kernel<<<1024, 256, 0, stream>>>(W0, GSp, e_v, a_v, memory, bank, m1);
  content_kernel<<<dim3(512, 2), 256, 0, stream>>>(m1, nullptr, kn, betaB, E1, RS1p);
  rheads_kernel<<<dim3(256, 4), 256, 0, stream>>>(E1, wr, m1, RS1p, g, gam, s, part, GSp);
  finalize_kernel<<<64, 1024, 0, stream>>>(part, GSp, (float*)d_out);
}

// Round 3
// 421.125 us; speedup vs baseline: 1.7386x; 1.1844x over previous
//
#include <hip/hip_runtime.h>

#define NN 65536
#define BB 64
#define HH 1024
#define MM 64
#define RR 4

__device__ __forceinline__ float waveReduceSum(float v) {
#pragma unroll
  for (int off = 32; off > 0; off >>= 1) v += __shfl_xor(v, off, 64);
  return v;
}

__device__ __forceinline__ float fastPow(float wt, float p) {
  return __expf(p * __logf(wt));
}

// shifted, gated interpolation weight at n (lane == n % 64). (used by wpow0)
__device__ __forceinline__ float shifted_wg(
    const float* __restrict__ Eb, const float* __restrict__ wb, int n,
    float gb, float rinv, float s0, float s1, float s2) {
  const int lane = threadIdx.x & 63;
  const float omg = 1.f - gb;
  const float wgc = gb * Eb[n] * rinv + omg * wb[n];
  float wgm = __shfl_up(wgc, 1, 64);
  float wgp = __shfl_down(wgc, 1, 64);
  if (lane == 0)  wgm = (n > 0)      ? (gb * Eb[n - 1] * rinv + omg * wb[n - 1]) : 0.f;
  if (lane == 63) wgp = (n < NN - 1) ? (gb * Eb[n + 1] * rinv + omg * wb[n + 1]) : 0.f;
  return s0 * wgm + s1 * wgc + s2 * wgp;
}

// ---------------------------------------------------------------------------
// K1: fused prep. grid 64 (one block per b), block 256.
// Also zero-inits RS0p/RS1p/GSp (contiguous 37888 floats at zbase).
// ---------------------------------------------------------------------------
__global__ __launch_bounds__(256) void prep_kernel(
    const float* __restrict__ h_t,
    const float* __restrict__ key_w, const float* __restrict__ key_b,
    const float* __restrict__ erase_w, const float* __restrict__ erase_b,
    const float* __restrict__ add_w, const float* __restrict__ add_b,
    const float* __restrict__ beta_w, const float* __restrict__ beta_b,
    const float* __restrict__ gate_w, const float* __restrict__ gate_b,
    const float* __restrict__ shift_w, const float* __restrict__ shift_b,
    const float* __restrict__ gamma_w, const float* __restrict__ gamma_b,
    float* __restrict__ kn, float* __restrict__ e_v, float* __restrict__ a_v,
    float* __restrict__ g, float* __restrict__ gamma_, float* __restrict__ s,
    float* __restrict__ betaGlob, float* __restrict__ zbase)
{
  const int b = blockIdx.x;
  const int t = threadIdx.x;
  for (int i = b * 256 + t; i < 37888; i += 16384) zbase[i] = 0.f;
  __shared__ float h_sh[HH];
  __shared__ float red[3][64][4];
  __shared__ float k_sh[64];
  ((float4*)h_sh)[t] = ((const float4*)(h_t + (size_t)b * HH))[t];
  __syncthreads();
  const int c = t & 63, q = t >> 6;
#pragma unroll
  for (int mat = 0; mat < 3; mat++) {
    const float* __restrict__ Wm = (mat == 0) ? key_w : ((mat == 1) ? erase_w : add_w);
    float d = 0.f;
#pragma unroll 8
    for (int i = 0; i < 256; i++)
      d += h_sh[q * 256 + i] * Wm[(q * 256 + i) * 64 + c];
    red[mat][c][q] = d;
  }
  __syncthreads();
  if (t < 64) {
    const float v = red[0][t][0] + red[0][t][1] + red[0][t][2] + red[0][t][3];
    k_sh[t] = fminf(fmaxf(v + key_b[t], 0.f), 1.f);
  } else if (t < 128) {
    const int c2 = t - 64;
    const float v = red[1][c2][0] + red[1][c2][1] + red[1][c2][2] + red[1][c2][3];
    e_v[b * 64 + c2] = fminf(fmaxf(v + erase_b[c2], 0.f), 1.f);
  } else if (t < 192) {
    const int c2 = t - 128;
    const float v = red[2][c2][0] + red[2][c2][1] + red[2][c2][2] + red[2][c2][3];
    a_v[b * 64 + c2] = fminf(fmaxf(v + add_b[c2], 0.f), 1.f);
  } else {
    const int lane = t - 192;
    float o0 = 0.f, o1 = 0.f, o2 = 0.f, o3 = 0.f, o4 = 0.f, o5 = 0.f;
#pragma unroll 4
    for (int k = 0; k < 16; k++) {
      const int hh = lane + k * 64;
      const float hv = h_sh[hh];
      o0 += hv * beta_w[hh];
      o1 += hv * gate_w[hh];
      o2 += hv * gamma_w[hh];
      o3 += hv * shift_w[hh * 3 + 0];
      o4 += hv * shift_w[hh * 3 + 1];
      o5 += hv * shift_w[hh * 3 + 2];
    }
    o0 = waveReduceSum(o0); o1 = waveReduceSum(o1); o2 = waveReduceSum(o2);
    o3 = waveReduceSum(o3); o4 = waveReduceSum(o4); o5 = waveReduceSum(o5);
    if (lane == 0) {
      betaGlob[b] = fmaxf(o0 + beta_b[0], 0.f);
      g[b]        = fminf(fmaxf(o1 + gate_b[0], 0.f), 1.f);
      gamma_[b]   = 1.0f + fmaxf(o2 + gamma_b[0], 0.f);
      const float l0 = o3 + shift_b[0], l1 = o4 + shift_b[1], l2 = o5 + shift_b[2];
      const float mx = fmaxf(l0, fmaxf(l1, l2));
      const float e0 = __expf(l0 - mx), e1 = __expf(l1 - mx), e2 = __expf(l2 - mx);
      const float inv = 1.f / (e0 + e1 + e2);
      s[b * 3 + 0] = e0 * inv; s[b * 3 + 1] = e1 * inv; s[b * 3 + 2] = e2 * inv;
    }
  }
  __syncthreads();
  if (t < 64) {
    float ss = 0.f;
    for (int j = 0; j < 64; j++) ss += k_sh[j] * k_sh[j];
    kn[b * 64 + t] = k_sh[t] / (sqrtf(ss) + 1e-8f);
  }
}

// ---------------------------------------------------------------------------
// K2 / K5: content addressing (round-0 proven). grid (512, 2), block 256.
// RS partials go to RSp[b*256 + slot*16], slot = blockIdx.x & 15.
// ---------------------------------------------------------------------------
__global__ __launch_bounds__(256) void content_kernel(
    const float* __restrict__ mem, const int* __restrict__ bank,
    const float* __restrict__ kn, const float* __restrict__ beta,
    float* __restrict__ E, float* __restrict__ RSp)
{
  const float* Mrow = mem + (bank ? ((size_t)(*bank) * (size_t)NN * MM) : (size_t)0);
  const int t = threadIdx.x;
  const int nl = t & 127;
  const int n = blockIdx.x * 128 + nl;
  const int bgrp = t >> 7;
  const int nhalf = (t >> 6) & 1;
  const int lane = t & 63;
  const int b0 = blockIdx.y * 32 + bgrp * 16;

  float4 row[16];
  const float4* rp = (const float4*)(Mrow + (size_t)n * MM);
#pragma unroll
  for (int q = 0; q < 16; q++) row[q] = rp[q];
  float ss = 0.f;
#pragma unroll
  for (int q = 0; q < 16; q++)
    ss += row[q].x * row[q].x + row[q].y * row[q].y + row[q].z * row[q].z + row[q].w * row[q].w;
  const float rinv = 1.0f / (sqrtf(ss) + 1e-8f);

  __shared__ float accs[32][2];
  for (int i = 0; i < 16; i++) {
    const int rb = __builtin_amdgcn_readfirstlane(b0 + i);
    const float4* kp = (const float4*)(kn + rb * 64);
    float dot = 0.f;
#pragma unroll
    for (int q = 0; q < 16; q++) {
      const float4 kq = kp[q];
      dot += kq.x * row[q].x + kq.y * row[q].y + kq.z * row[q].z + kq.w * row[q].w;
    }
    const float e = __expf(beta[rb] * dot * rinv);
    E[(size_t)rb * NN + n] = e;
    const float r = waveReduceSum(e);
    if (lane == 0) accs[bgrp * 16 + i][nhalf] = r;
  }
  __syncthreads();
  if (t < 32)
    atomicAdd(&RSp[(blockIdx.y * 32 + t) * 256 + (blockIdx.x & 15) * 16],
              accs[t][0] + accs[t][1]);
}

// ---------------------------------------------------------------------------
// K3: streaming w_pow producer for the WRITE head. grid (64, 64), block 256.
// ---------------------------------------------------------------------------
__global__ __launch_bounds__(256) void wpow_kernel(
    const float* __restrict__ E, const float* __restrict__ wprev,
    const float* __restrict__ RSp, const float* __restrict__ g,
    const float* __restrict__ gamma_, const float* __restrict__ s,
    float* __restrict__ W, float* __restrict__ GSp, int slot)
{
  const int b = blockIdx.y;
  const float gb = g[b], gmb = gamma_[b];
  const float s0 = s[b * 3], s1 = s[b * 3 + 1], s2 = s[b * 3 + 2];
  float rs = 0.f;
#pragma unroll
  for (int j = 0; j < 16; j++) rs += RSp[b * 256 + j * 16];
  const float rinv = 1.0f / rs;
  const float* Eb = E + (size_t)b * NN;
  const float* wb = wprev + (size_t)b * NN;
  float* Wb = W + (size_t)b * NN;
  const int base = blockIdx.x * 1024;
  float acc = 0.f;
#pragma unroll
  for (int k = 0; k < 4; k++) {
    const int n = base + k * 256 + threadIdx.x;
    const float wt = shifted_wg(Eb, wb, n, gb, rinv, s0, s1, s2);
    const float wp = fastPow(wt, gmb);
    Wb[n] = wp;
    acc += wp;
  }
  __shared__ float wsum[4];
  const float w = waveReduceSum(acc);
  if ((threadIdx.x & 63) == 0) wsum[threadIdx.x >> 6] = w;
  __syncthreads();
  if (threadIdx.x == 0)
    atomicAdd(&GSp[slot * 1024 + b * 16], wsum[0] + wsum[1] + wsum[2] + wsum[3]);
}

// ---------------------------------------------------------------------------
// K4: apply write head (round-0 proven). grid 1024 (64-n), block 256.
// ---------------------------------------------------------------------------
__global__ __launch_bounds__(256) void apply_write_kernel(
    const float* __restrict__ W0, const float* __restrict__ GSp,
    const float* __restrict__ e_v, const float* __restrict__ a_v,
    const float* __restrict__ memory, const int* __restrict__ bank,
    float* __restrict__ m1)
{
  __shared__ float cw[64 * 68];
  __shared__ float e_sh[4096];
  __shared__ float a_sh[4096];
  const int t = threadIdx.x;
  const int n0 = blockIdx.x * 64;
  float gs = 0.f;
#pragma unroll
  for (int j = 0; j < 64; j++) gs += GSp[j * 16];
  const float invGS = 1.0f / (gs + 1e-5f);
#pragma unroll
  for (int q = 0; q < 4; q++) {
    ((float4*)e_sh)[t + 256 * q] = ((const float4*)e_v)[t + 256 * q];
    ((float4*)a_sh)[t + 256 * q] = ((const float4*)a_v)[t + 256 * q];
  }
#pragma unroll
  for (int rep = 0; rep < 4; rep++) {
    const int idx = rep * 256 + t;
    const int b = idx >> 4, nc = idx & 15;
    float4 v = *((const float4*)(W0 + (size_t)b * NN + n0 + nc * 4));
    v.x *= invGS; v.y *= invGS; v.z *= invGS; v.w *= invGS;
    *((float4*)&cw[b * 68 + nc * 4]) = v;
  }
  __syncthreads();
  const int nl = t >> 2, mq = t & 3;
  const int n = n0 + nl;
  float er[16], ad[16];
#pragma unroll
  for (int j = 0; j < 16; j++) { er[j] = 0.f; ad[j] = 0.f; }
  for (int b = 0; b < 64; b++) {
    const float c = cw[b * 68 + nl];
#pragma unroll
    for (int j = 0; j < 4; j++) {
      const float4 ev = *((const float4*)&e_sh[b * 64 + mq * 16 + j * 4]);
      const float4 av = *((const float4*)&a_sh[b * 64 + mq * 16 + j * 4]);
      er[j * 4 + 0] += c * ev.x; er[j * 4 + 1] += c * ev.y;
      er[j * 4 + 2] += c * ev.z; er[j * 4 + 3] += c * ev.w;
      ad[j * 4 + 0] += c * av.x; ad[j * 4 + 1] += c * av.y;
      ad[j * 4 + 2] += c * av.z; ad[j * 4 + 3] += c * av.w;
    }
  }
  const float* M0 = memory + (size_t)(*bank) * (size_t)NN * MM;
  const float4* m0p = (const float4*)(M0 + (size_t)n * MM + mq * 16);
  float4* m1p = (float4*)(m1 + (size_t)n * MM + mq * 16);
#pragma unroll
  for (int j = 0; j < 4; j++) {
    const float4 mv = m0p[j];
    float4 o;
    o.x = mv.x * (1.f - er[j * 4 + 0]) + ad[j * 4 + 0];
    o.y = mv.y * (1.f - er[j * 4 + 1]) + ad[j * 4 + 1];
    o.z = mv.z * (1.f - er[j * 4 + 2]) + ad[j * 4 + 2];
    o.w = mv.w * (1.f - er[j * 4 + 3]) + ad[j * 4 + 3];
    m1p[j] = o;
  }
}

// ---------------------------------------------------------------------------
// K6: per-r fused wpow+gemm. grid (512, 4): blockIdx.x = sc, blockIdx.y = r.
// Each block: 2 sub-tiles of 64 n. w_pow tile -> LDS TRANSPOSED [n][b] (pad 68)
// so gemm reads w as one ds_read_b128. m1 read directly from global (L2-hot),
// no m1_sh -> LDS 17.4KB -> 8 blocks/CU. part[r][512][4096] + GS partials.
// ---------------------------------------------------------------------------
__global__ __launch_bounds__(256) void rheads_kernel(
    const float* __restrict__ E, const float* __restrict__ wr,
    const float* __restrict__ m1, const float* __restrict__ RSp,
    const float* __restrict__ g, const float* __restrict__ gamma_,
    const float* __restrict__ s,
    float* __restrict__ part, float* __restrict__ GSp)
{
  __shared__ float g_sh[64], gm_sh[64], ri_sh[64];
  __shared__ float s0_sh[64], s1_sh[64], s2_sh[64];
  __shared__ float w_shT[64 * 68];   // [n_local][b], pad 68 for write conflicts
  __shared__ float gsred[4];
  const int sc = blockIdx.x, r = blockIdx.y;
  const int t = threadIdx.x;
  if (t < 64) {
    float rs = 0.f;
#pragma unroll
    for (int j = 0; j < 16; j++) rs += RSp[t * 256 + j * 16];
    ri_sh[t] = 1.0f / rs;
    g_sh[t] = g[t];
    gm_sh[t] = gamma_[t];
    s0_sh[t] = s[t * 3 + 0];
    s1_sh[t] = s[t * 3 + 1];
    s2_sh[t] = s[t * 3 + 2];
  }
  __syncthreads();
  const int n_l = t & 63, bg = t >> 6;
  const int bq = t >> 4, mq = t & 15;
  const float* __restrict__ wrr = wr + (size_t)r * BB * NN;
  float4 acc[4];
#pragma unroll
  for (int j = 0; j < 4; j++) acc[j] = make_float4(0.f, 0.f, 0.f, 0.f);
  float gs_acc = 0.f;

  for (int st = 0; st < 2; st++) {
    if (st) __syncthreads();  // gemm finished reading w_shT
    const int n0 = (sc * 2 + st) * 64;
    const int n = n0 + n_l;
    // ---- produce w tile: wave bg owns b in [bg*16, bg*16+16) ----
#pragma unroll
    for (int half = 0; half < 2; half++) {
      float ev[8], wv[8];
#pragma unroll
      for (int j = 0; j < 8; j++) {
        const int b = bg * 16 + half * 8 + j;
        ev[j] = E[(size_t)b * NN + n];
        wv[j] = wrr[(size_t)b * NN + n];
      }
#pragma unroll
      for (int j = 0; j < 8; j++) {
        const int b = bg * 16 + half * 8 + j;
        const float gri = g_sh[b] * ri_sh[b];
        const float omg = 1.f - g_sh[b];
        const float wgc = gri * ev[j] + omg * wv[j];
        float wgm = __shfl_up(wgc, 1, 64);
        float wgp = __shfl_down(wgc, 1, 64);
        if (n_l == 0)
          wgm = (n > 0) ? (gri * E[(size_t)b * NN + n - 1] + omg * wrr[(size_t)b * NN + n - 1]) : 0.f;
        if (n_l == 63)
          wgp = (n < NN - 1) ? (gri * E[(size_t)b * NN + n + 1] + omg * wrr[(size_t)b * NN + n + 1]) : 0.f;
        const float wt = s0_sh[b] * wgm + s1_sh[b] * wgc + s2_sh[b] * wgp;
        const float wp = fastPow(wt, gm_sh[b]);
        w_shT[n_l * 68 + b] = wp;
        gs_acc += wp;
      }
    }
    __syncthreads();
    // ---- gemm accumulate: thread (bq, mq): 4 b x 4 m; m1 from global/L2 ----
    const float4* __restrict__ m1p = (const float4*)(m1 + (size_t)n0 * MM);
#pragma unroll 4
    for (int nn = 0; nn < 64; nn++) {
      const float4 mv = m1p[nn * 16 + mq];
      const float4 wv4 = *((const float4*)&w_shT[nn * 68 + bq * 4]);
      acc[0].x += wv4.x * mv.x; acc[0].y += wv4.x * mv.y; acc[0].z += wv4.x * mv.z; acc[0].w += wv4.x * mv.w;
      acc[1].x += wv4.y * mv.x; acc[1].y += wv4.y * mv.y; acc[1].z += wv4.y * mv.z; acc[1].w += wv4.y * mv.w;
      acc[2].x += wv4.z * mv.x; acc[2].y += wv4.z * mv.y; acc[2].z += wv4.z * mv.z; acc[2].w += wv4.z * mv.w;
      acc[3].x += wv4.w * mv.x; acc[3].y += wv4.w * mv.y; acc[3].z += wv4.w * mv.z; acc[3].w += wv4.w * mv.w;
    }
  }
  float* pp = part + ((size_t)r * 512 + sc) * 4096;
#pragma unroll
  for (int j = 0; j < 4; j++)
    *((float4*)&pp[(bq * 4 + j) * 64 + mq * 4]) = acc[j];
  const float v = waveReduceSum(gs_acc);
  if (n_l == 0) gsred[bg] = v;
  __syncthreads();
  if (t == 0)
    atomicAdd(&GSp[(1 + r) * 1024 + (sc & 63) * 16],
              gsred[0] + gsred[1] + gsred[2] + gsred[3]);
}

// ---------------------------------------------------------------------------
// K7: reduce part[4][512][4096] + GS normalize. grid 64 (b), block 1024.
// ---------------------------------------------------------------------------
__global__ __launch_bounds__(1024) void finalize_kernel(
    const float* __restrict__ part, const float* __restrict__ GSp,
    float* __restrict__ out)
{
  __shared__ float gs_sh[4];
  __shared__ float red[4][256];
  const int t = threadIdx.x;
  if (t < 256) {
    const int wv = t >> 6, ln = t & 63;
    float v = GSp[(1 + wv) * 1024 + ln * 16];
    v = waveReduceSum(v);
    if (ln == 0) gs_sh[wv] = v;
  }
  const int b = blockIdx.x;
  const int q = t >> 8;        // slab quarter 0..3 (128 slabs each)
  const int e = t & 255;       // r*64 + m
  const int r = e >> 6, m = e & 63;
  float sum = 0.f;
  const float* pp = part + (size_t)r * 512 * 4096 + (size_t)b * 64 + m;
#pragma unroll 8
  for (int k = q * 128; k < q * 128 + 128; k++)
    sum += pp[(size_t)k * 4096];
  red[q][e] = sum;
  __syncthreads();
  if (t < 256) {
    const float tot = red[0][t] + red[1][t] + red[2][t] + red[3][t];
    out[b * 256 + t] = tot / (gs_sh[t >> 6] + 1e-5f);
  }
}

// ---------------------------------------------------------------------------
extern "C" void kernel_launch(void* const* d_in, const int* in_sizes, int n_in,
                              void* d_out, int out_size, void* d_ws, size_t ws_size,
                              hipStream_t stream) {
  (void)in_sizes; (void)n_in; (void)out_size; (void)ws_size;
  const float* h_t    = (const float*)d_in[0];
  const float* ww     = (const float*)d_in[1];
  const float* wr     = (const float*)d_in[2];
  const float* memory = (const float*)d_in[3];
  const float* key_w  = (const float*)d_in[4];
  const float* key_b  = (const float*)d_in[5];
  const float* beta_w = (const float*)d_in[6];
  const float* beta_b = (const float*)d_in[7];
  const float* gate_w = (const float*)d_in[8];
  const float* gate_b = (const float*)d_in[9];
  const float* shift_w = (const float*)d_in[10];
  const float* shift_b = (const float*)d_in[11];
  const float* gamma_w = (const float*)d_in[12];
  const float* gamma_b = (const float*)d_in[13];
  const float* erase_w = (const float*)d_in[14];
  const float* erase_b = (const float*)d_in[15];
  const float* add_w   = (const float*)d_in[16];
  const float* add_b   = (const float*)d_in[17];
  const int*   bank    = (const int*)d_in[18];

  float* ws = (float*)d_ws;
  // slabs (floats): E0 @0, W0 @4M, m1 @8M, E1 @12M, smallb @16M,
  // part @20M (4 x 512 x 4096 = 8.39M floats = 33.5MB).
  float* E0   = ws;
  float* W0   = ws + 4194304;
  float* m1   = ws + 8388608;
  float* E1   = ws + 12582912;
  float* smallb = ws + 16777216;
  float* part = ws + 20971520;
  float* kn    = smallb;            // 4096
  float* e_v   = smallb + 4096;     // 4096
  float* a_v   = smallb + 8192;     // 4096
  float* betaB = smallb + 12288;    // 64
  float* g     = smallb + 12352;    // 64
  float* gam   = smallb + 12416;    // 64
  float* s     = smallb + 12480;    // 256 (192 used)
  float* RS0p  = smallb + 12800;    // 16384 (64 b x 16 slots x 16 pad)
  float* RS1p  = smallb + 29184;    // 16384
  float* GSp   = smallb + 45568;    // 5120 (5 slots x 64 x 16 pad)
  // RS0p/RS1p/GSp contiguous: zero range = smallb+12800 .. +50688

  prep_kernel<<<64, 256, 0, stream>>>(
      h_t, key_w, key_b, erase_w, erase_b, add_w, add_b,
      beta_w, beta_b, gate_w, gate_b, shift_w, shift_b, gamma_w, gamma_b,
      kn, e_v, a_v, g, gam, s, betaB, smallb + 12800);
  content_kernel<<<dim3(512, 2), 256, 0, stream>>>(memory, bank, kn, betaB, E0, RS0p);
  wpow_kernel<<<dim3(64, 64), 256, 0, stream>>>(E0, ww, RS0p, g, gam, s, W0, GSp, 0);
  apply_write_kernel<<<1024, 256, 0, stream>>>(W0, GSp, e_v, a_v, memory, bank, m1);
  content_kernel<<<dim3(512, 2), 256, 0, stream>>>(m1, nullptr, kn, betaB, E1, RS1p);
  rheads_kernel<<<dim3(512, 4), 256, 0, stream>>>(E1, wr, m1, RS1p, g, gam, s, part, GSp);
  finalize_kernel<<<64, 1024, 0, stream>>>(part, GSp, (float*)d_out);
}